// Round 5
// baseline (659.275 us; speedup 1.0000x reference)
//
#include <hip/hip_runtime.h>
#include <math.h>

// ---------------------------------------------------------------------------
// GraphSAGE fraud detector. CSR-gather aggregation + bf16 MFMA GEMMs.
// R5: R4 minus the __launch_bounds__(256,3) register cap (it forced the
// f32x4 acc[4][4] accumulators to spill to scratch: 783 MB WRITE_SIZE,
// MfmaUtil 6.7%). Keep BK=64, grid (colblk,rowblk) swizzle, hierarchical
// scan, bf16 gather_128.
// MFMA 16x16x32 bf16: A-frag A[m=lane&15][k=quad*8+j]; C/D col=lane&15,
// row=quad*4+reg (m89/m97-verified layouts).
// ---------------------------------------------------------------------------

typedef __attribute__((ext_vector_type(8))) short bf16x8;   // 8 bf16, 4 VGPRs
typedef __attribute__((ext_vector_type(4))) float f32x4;

static inline int ceil_div(int a, int b) { return (a + b - 1) / b; }

__device__ inline float bf2f_lo(unsigned u) { return __builtin_bit_cast(float, u << 16); }
__device__ inline float bf2f_hi(unsigned u) { return __builtin_bit_cast(float, u & 0xffff0000u); }
__device__ inline unsigned f2bf(float f) {   // RNE round to bf16, bits in low 16
    unsigned u = __builtin_bit_cast(unsigned, f);
    u += 0x7fffu + ((u >> 16) & 1u);
    return u >> 16;
}

// ---------------- CSR build ----------------

__global__ void hist_kernel(const int* __restrict__ dst, int* __restrict__ deg, int E) {
    int e = blockIdx.x * 256 + threadIdx.x;
    if (e < E) atomicAdd(&deg[dst[e]], 1);
}

// per-1024-chunk sums
__global__ __launch_bounds__(256) void chunk_reduce(const int* __restrict__ deg,
                                                    int* __restrict__ partial, int N) {
    int base = blockIdx.x * 1024;
    int s = 0;
    for (int i = threadIdx.x; i < 1024; i += 256) {
        int idx = base + i;
        if (idx < N) s += deg[idx];
    }
    #pragma unroll
    for (int off = 32; off; off >>= 1) s += __shfl_down(s, off);
    __shared__ int ws[4];
    if ((threadIdx.x & 63) == 0) ws[threadIdx.x >> 6] = s;
    __syncthreads();
    if (threadIdx.x == 0) partial[blockIdx.x] = ws[0] + ws[1] + ws[2] + ws[3];
}

// exclusive scan of P<=64 partials (one wave); writes rowstart[N]=total
__global__ void partial_scan(int* __restrict__ partial, int* __restrict__ rowstartN, int P) {
    int lane = threadIdx.x;
    int v = (lane < P) ? partial[lane] : 0;
    int incl = v;
    #pragma unroll
    for (int off = 1; off < 64; off <<= 1) {
        int t = __shfl_up(incl, off);
        if (lane >= off) incl += t;
    }
    if (lane < P) partial[lane] = incl - v;
    if (lane == 63) *rowstartN = incl;
}

// per-chunk exclusive scan + global offset; writes rowstart and cursor
__global__ __launch_bounds__(256) void chunk_scan(const int* __restrict__ deg,
                                                  const int* __restrict__ partial,
                                                  int* __restrict__ rowstart,
                                                  int* __restrict__ cursor, int N) {
    int base = blockIdx.x * 1024 + threadIdx.x * 4;
    int v[4];
    #pragma unroll
    for (int j = 0; j < 4; ++j) {
        int i = base + j;
        v[j] = (i < N) ? deg[i] : 0;
    }
    int mysum = v[0] + v[1] + v[2] + v[3];
    int incl = mysum;
    int lane = threadIdx.x & 63, wave = threadIdx.x >> 6;
    #pragma unroll
    for (int off = 1; off < 64; off <<= 1) {
        int t = __shfl_up(incl, off);
        if (lane >= off) incl += t;
    }
    __shared__ int ws[4];
    if (lane == 63) ws[wave] = incl;
    __syncthreads();
    int run = partial[blockIdx.x] + incl - mysum;
    for (int w = 0; w < wave; ++w) run += ws[w];
    #pragma unroll
    for (int j = 0; j < 4; ++j) {
        int i = base + j;
        if (i < N) { rowstart[i] = run; cursor[i] = run; }
        run += v[j];
    }
}

__global__ void bucket_kernel(const int* __restrict__ src, const int* __restrict__ dst,
                              int* __restrict__ cursor, int* __restrict__ ebuf, int E) {
    int e = blockIdx.x * 256 + threadIdx.x;
    if (e < E) {
        int pos = atomicAdd(&cursor[dst[e]], 1);
        ebuf[pos] = src[e];
    }
}

// ---------------- dtype conversion ----------------

__global__ void cvt_bf16_kernel(const float* __restrict__ in, unsigned short* __restrict__ out, int n4) {
    int i = blockIdx.x * 256 + threadIdx.x;
    if (i < n4) {
        float4 v = ((const float4*)in)[i];
        ushort4 o;
        o.x = (unsigned short)f2bf(v.x);
        o.y = (unsigned short)f2bf(v.y);
        o.z = (unsigned short)f2bf(v.z);
        o.w = (unsigned short)f2bf(v.w);
        ((ushort4*)out)[i] = o;
    }
}

// ---------------- gather means ----------------

// one wave per dst row; bf16 xb [N,128] -> bf16 mean [N,128]; fp32 accum
__global__ void gather_mean_128(const int* __restrict__ rowstart, const int* __restrict__ ebuf,
                                const unsigned* __restrict__ featb, unsigned* __restrict__ outb, int N) {
    int w = (blockIdx.x * blockDim.x + threadIdx.x) >> 6;
    int lane = threadIdx.x & 63;
    if (w >= N) return;
    int e0 = rowstart[w], e1 = rowstart[w + 1];
    float ax = 0.0f, ay = 0.0f;
    for (int i = e0; i < e1; ++i) {
        int s = ebuf[i];
        unsigned v = featb[(size_t)s * 64 + lane];   // 2 bf16
        ax += bf2f_lo(v); ay += bf2f_hi(v);
    }
    float inv = 1.0f / fmaxf((float)(e1 - e0), 1.0f);
    outb[(size_t)w * 64 + lane] = f2bf(ax * inv) | (f2bf(ay * inv) << 16);
}

// one wave per dst row; bf16 feat [N,512] -> bf16 mean [N,512]; fp32 accum
__global__ void gather_mean_512(const int* __restrict__ rowstart, const int* __restrict__ ebuf,
                                const unsigned short* __restrict__ featb,
                                unsigned short* __restrict__ outb, int N) {
    int w = (blockIdx.x * blockDim.x + threadIdx.x) >> 6;
    int lane = threadIdx.x & 63;
    if (w >= N) return;
    int e0 = rowstart[w], e1 = rowstart[w + 1];
    float a[8] = {0, 0, 0, 0, 0, 0, 0, 0};
    const uint4* base = (const uint4*)featb;     // 512 bf16/row = 64 uint4/row
    for (int i = e0; i < e1; ++i) {
        int s = ebuf[i];
        uint4 v = base[(size_t)s * 64 + lane];
        a[0] += bf2f_lo(v.x); a[1] += bf2f_hi(v.x);
        a[2] += bf2f_lo(v.y); a[3] += bf2f_hi(v.y);
        a[4] += bf2f_lo(v.z); a[5] += bf2f_hi(v.z);
        a[6] += bf2f_lo(v.w); a[7] += bf2f_hi(v.w);
    }
    float inv = 1.0f / fmaxf((float)(e1 - e0), 1.0f);
    uint4 o;
    o.x = f2bf(a[0] * inv) | (f2bf(a[1] * inv) << 16);
    o.y = f2bf(a[2] * inv) | (f2bf(a[3] * inv) << 16);
    o.z = f2bf(a[4] * inv) | (f2bf(a[5] * inv) << 16);
    o.w = f2bf(a[6] * inv) | (f2bf(a[7] * inv) << 16);
    ((uint4*)outb)[(size_t)w * 64 + lane] = o;
}

// ---------------- bf16 MFMA GEMM ----------------
// C = relu([A0b | A1b] @ Wb^T + b)
// mode 0: store C as bf16 to outb [N, C]
// mode 1: logit[row] += sum_col C[row,col] * Wo[col]
// Block 256 thr = 4 waves (2x2); tile 128x128; wave tile 64x64 (4x4 mfma);
// BK=64 -> 32 MFMA per barrier-pair. grid = (colblk, rowblk): col siblings
// dispatch-adjacent so A tile stays L2/L3-hot.
// NOTE: no min-waves bound — (256,3) capped VGPRs at 64 and spilled the
// accumulators (R4: 783 MB scratch writes, MfmaUtil 6.7%).
__global__ __launch_bounds__(256) void gemm_mfma(
    const unsigned short* __restrict__ A0,   // [N, K0] bf16
    const unsigned short* __restrict__ A1,   // [N, K1] bf16
    const unsigned short* __restrict__ W,    // [C, K0+K1] bf16 row-major
    const float* __restrict__ b,             // [C] fp32
    unsigned short* __restrict__ outb,       // [N, C] bf16 (mode 0)
    const float* __restrict__ Wo,            // [C] fp32    (mode 1)
    float* __restrict__ logit,               // [N] fp32    (mode 1)
    int N, int K0, int K1, int C, int mode)
{
    const int K = K0 + K1;
    // row stride 72 shorts = 144 B (16B-aligned; frag-read lanes cl,cl+8 alias
    // -> 2-way, free per m136)
    __shared__ short As[128 * 72];
    __shared__ short Bs[128 * 72];

    const int tid  = threadIdx.x;
    const int lane = tid & 63;
    const int wave = tid >> 6;
    const int wm = wave & 1, wn = wave >> 1;
    const int cl = lane & 15, quad = lane >> 4;
    const int row0 = blockIdx.y * 128;
    const int col0 = blockIdx.x * 128;

    // staging: thread t loads 64 B (4x uint4) of one row-half (k off shalf*32)
    const int srow  = tid >> 1;     // 0..127
    const int shalf = tid & 1;      // 0/1
    const int arow = row0 + srow;
    const bool aok = arow < N;
    const int wcol = col0 + srow;   // C multiple of 128 -> always valid

    f32x4 acc[4][4];
    #pragma unroll
    for (int mt = 0; mt < 4; ++mt)
        #pragma unroll
        for (int nt = 0; nt < 4; ++nt)
            acc[mt][nt] = (f32x4){0.f, 0.f, 0.f, 0.f};

    for (int k0 = 0; k0 < K; k0 += 64) {
        const int gk = k0 + shalf * 32;
        uint4 av[4] = {{0,0,0,0},{0,0,0,0},{0,0,0,0},{0,0,0,0}};
        if (aok) {
            const uint4* p;
            if (gk < K0)     // K0 multiple of 64 -> uniform per shalf
                p = (const uint4*)(A0 + (size_t)arow * K0 + gk);
            else
                p = (const uint4*)(A1 + (size_t)arow * K1 + (gk - K0));
            av[0] = p[0]; av[1] = p[1]; av[2] = p[2]; av[3] = p[3];
        }
        const uint4* wp = (const uint4*)(W + (size_t)wcol * K + gk);
        uint4 wv[4] = {wp[0], wp[1], wp[2], wp[3]};

        __syncthreads();    // previous iteration's frag reads done
        {
            short* pa = &As[srow * 72 + shalf * 32];
            short* pb = &Bs[srow * 72 + shalf * 32];
            #pragma unroll
            for (int j = 0; j < 4; ++j) {
                *(uint4*)(pa + j * 8) = av[j];
                *(uint4*)(pb + j * 8) = wv[j];
            }
        }
        __syncthreads();

        #pragma unroll
        for (int kk = 0; kk < 2; ++kk) {
            bf16x8 af[4], bfr[4];
            #pragma unroll
            for (int mt = 0; mt < 4; ++mt)
                af[mt] = *(const bf16x8*)&As[(wm * 64 + mt * 16 + cl) * 72 + kk * 32 + quad * 8];
            #pragma unroll
            for (int nt = 0; nt < 4; ++nt)
                bfr[nt] = *(const bf16x8*)&Bs[(wn * 64 + nt * 16 + cl) * 72 + kk * 32 + quad * 8];
            #pragma unroll
            for (int mt = 0; mt < 4; ++mt)
                #pragma unroll
                for (int nt = 0; nt < 4; ++nt)
                    acc[mt][nt] = __builtin_amdgcn_mfma_f32_16x16x32_bf16(
                        af[mt], bfr[nt], acc[mt][nt], 0, 0, 0);
        }
    }

    if (mode == 0) {
        #pragma unroll
        for (int nt = 0; nt < 4; ++nt) {
            const int colb = col0 + wn * 64 + nt * 16 + cl;
            const float bb = b[colb];
            #pragma unroll
            for (int mt = 0; mt < 4; ++mt) {
                #pragma unroll
                for (int r = 0; r < 4; ++r) {
                    int row = row0 + wm * 64 + mt * 16 + quad * 4 + r;
                    if (row < N)
                        outb[(size_t)row * C + colb] =
                            (unsigned short)f2bf(fmaxf(acc[mt][nt][r] + bb, 0.0f));
                }
            }
        }
    } else {
        float bv[4], wv2[4];
        #pragma unroll
        for (int nt = 0; nt < 4; ++nt) {
            const int colb = col0 + wn * 64 + nt * 16 + cl;
            bv[nt] = b[colb];
            wv2[nt] = Wo[colb];
        }
        #pragma unroll
        for (int mt = 0; mt < 4; ++mt) {
            #pragma unroll
            for (int r = 0; r < 4; ++r) {
                float s = 0.0f;
                #pragma unroll
                for (int nt = 0; nt < 4; ++nt)
                    s += fmaxf(acc[mt][nt][r] + bv[nt], 0.0f) * wv2[nt];
                s += __shfl_xor(s, 1);
                s += __shfl_xor(s, 2);
                s += __shfl_xor(s, 4);
                s += __shfl_xor(s, 8);
                int row = row0 + wm * 64 + mt * 16 + quad * 4 + r;
                if (cl == 0 && row < N) atomicAdd(&logit[row], s);
            }
        }
    }
}

__global__ void head_kernel(const float* __restrict__ logit, const float* __restrict__ bo,
                            float* __restrict__ out, int N) {
    int i = blockIdx.x * 256 + threadIdx.x;
    if (i < N) out[i] = 1.0f / (1.0f + expf(-(logit[i] + bo[0])));
}

extern "C" void kernel_launch(void* const* d_in, const int* in_sizes, int n_in,
                              void* d_out, int out_size, void* d_ws, size_t ws_size,
                              hipStream_t stream) {
    const float* x  = (const float*)d_in[0];
    const int*   ei = (const int*)d_in[1];
    const float* W1 = (const float*)d_in[2];
    const float* b1 = (const float*)d_in[3];
    const float* W2 = (const float*)d_in[4];
    const float* b2 = (const float*)d_in[5];
    const float* Wo = (const float*)d_in[6];
    const float* bo = (const float*)d_in[7];
    float* out = (float*)d_out;

    const int N = in_sizes[0] / 128;   // 50000
    const int E = in_sizes[1] / 2;     // 400000
    const int* src = ei;
    const int* dst = ei + E;

    char* ws = (char*)d_ws;
    size_t off = 0;
    auto alloc = [&](size_t bytes) {
        void* p = ws + off;
        off += (bytes + 255) & ~(size_t)255;
        return p;
    };
    int* deg      = (int*)alloc((size_t)N * 4);
    int* rowstart = (int*)alloc((size_t)(N + 1) * 4);
    int* cursor   = (int*)alloc((size_t)N * 4);
    int* partial  = (int*)alloc((size_t)64 * 4);
    int* ebuf     = (int*)alloc((size_t)E * 4);
    float* logit  = (float*)alloc((size_t)N * 4);
    unsigned short* xb  = (unsigned short*)alloc((size_t)N * 128 * 2);
    unsigned short* W1b = (unsigned short*)alloc((size_t)512 * 256 * 2);
    unsigned short* W2b = (unsigned short*)alloc((size_t)512 * 1024 * 2);
    unsigned short* n1b = (unsigned short*)alloc((size_t)N * 128 * 2);
    unsigned short* h1b = (unsigned short*)alloc((size_t)N * 512 * 2);
    unsigned short* n2b = (unsigned short*)alloc((size_t)N * 512 * 2);
    (void)ws_size; (void)n_in; (void)out_size;

    hipMemsetAsync(deg,   0, (size_t)N * 4, stream);
    hipMemsetAsync(logit, 0, (size_t)N * 4, stream);

    // conversions
    cvt_bf16_kernel<<<ceil_div(N * 128 / 4, 256), 256, 0, stream>>>(x, xb, N * 128 / 4);
    cvt_bf16_kernel<<<ceil_div(512 * 256 / 4, 256), 256, 0, stream>>>(W1, W1b, 512 * 256 / 4);
    cvt_bf16_kernel<<<ceil_div(512 * 1024 / 4, 256), 256, 0, stream>>>(W2, W2b, 512 * 1024 / 4);

    // CSR build (hierarchical scan)
    const int P = ceil_div(N, 1024);   // 49
    hist_kernel<<<ceil_div(E, 256), 256, 0, stream>>>(dst, deg, E);
    chunk_reduce<<<P, 256, 0, stream>>>(deg, partial, N);
    partial_scan<<<1, 64, 0, stream>>>(partial, rowstart + N, P);
    chunk_scan<<<P, 256, 0, stream>>>(deg, partial, rowstart, cursor, N);
    bucket_kernel<<<ceil_div(E, 256), 256, 0, stream>>>(src, dst, cursor, ebuf, E);

    dim3 gg(512 / 128, ceil_div(N, 128));   // (colblk fast, rowblk slow)

    // layer 1
    gather_mean_128<<<ceil_div(N * 64, 256), 256, 0, stream>>>(rowstart, ebuf,
                                                               (const unsigned*)xb, (unsigned*)n1b, N);
    gemm_mfma<<<gg, 256, 0, stream>>>(xb, n1b, W1b, b1, h1b, nullptr, nullptr,
                                      N, 128, 128, 512, 0);

    // layer 2 + fused head
    gather_mean_512<<<ceil_div(N * 64, 256), 256, 0, stream>>>(rowstart, ebuf, h1b, n2b, N);
    gemm_mfma<<<gg, 256, 0, stream>>>(h1b, n2b, W2b, b2, nullptr, Wo, logit,
                                      N, 512, 512, 512, 1);

    head_kernel<<<ceil_div(N, 256), 256, 0, stream>>>(logit, bo, out, N);
}

// Round 6
// 400.513 us; speedup vs baseline: 1.6461x; 1.6461x over previous
//
#include <hip/hip_runtime.h>
#include <math.h>

// ---------------------------------------------------------------------------
// GraphSAGE fraud detector. CSR-gather aggregation + bf16 MFMA GEMMs.
// R6: gemm reverted to R3 body (BK=32, scalar staging — proven spill-free;
// the R4/R5 BK=64 variant spilled acc to scratch regardless of
// launch_bounds: 748 MB scratch writes, MfmaUtil 6.6%). Only the grid
// ordering keeps R4's (colblk fast, rowblk slow) so the 4 column-siblings
// of each A row-tile are dispatch-concurrent and share one fetch via L2/L3.
// Aux path keeps R5 wins: hierarchical scan, bf16 gather_128.
// MFMA 16x16x32 bf16: A-frag A[m=lane&15][k=quad*8+j]; C/D col=lane&15,
// row=quad*4+reg (m89/m97-verified layouts).
// ---------------------------------------------------------------------------

typedef __attribute__((ext_vector_type(8))) short bf16x8;   // 8 bf16, 4 VGPRs
typedef __attribute__((ext_vector_type(4))) float f32x4;

static inline int ceil_div(int a, int b) { return (a + b - 1) / b; }

__device__ inline float bf2f_lo(unsigned u) { return __builtin_bit_cast(float, u << 16); }
__device__ inline float bf2f_hi(unsigned u) { return __builtin_bit_cast(float, u & 0xffff0000u); }
__device__ inline unsigned f2bf(float f) {   // RNE round to bf16, bits in low 16
    unsigned u = __builtin_bit_cast(unsigned, f);
    u += 0x7fffu + ((u >> 16) & 1u);
    return u >> 16;
}

// ---------------- CSR build ----------------

__global__ void hist_kernel(const int* __restrict__ dst, int* __restrict__ deg, int E) {
    int e = blockIdx.x * 256 + threadIdx.x;
    if (e < E) atomicAdd(&deg[dst[e]], 1);
}

// per-1024-chunk sums
__global__ __launch_bounds__(256) void chunk_reduce(const int* __restrict__ deg,
                                                    int* __restrict__ partial, int N) {
    int base = blockIdx.x * 1024;
    int s = 0;
    for (int i = threadIdx.x; i < 1024; i += 256) {
        int idx = base + i;
        if (idx < N) s += deg[idx];
    }
    #pragma unroll
    for (int off = 32; off; off >>= 1) s += __shfl_down(s, off);
    __shared__ int ws[4];
    if ((threadIdx.x & 63) == 0) ws[threadIdx.x >> 6] = s;
    __syncthreads();
    if (threadIdx.x == 0) partial[blockIdx.x] = ws[0] + ws[1] + ws[2] + ws[3];
}

// exclusive scan of P<=64 partials (one wave); writes rowstart[N]=total
__global__ void partial_scan(int* __restrict__ partial, int* __restrict__ rowstartN, int P) {
    int lane = threadIdx.x;
    int v = (lane < P) ? partial[lane] : 0;
    int incl = v;
    #pragma unroll
    for (int off = 1; off < 64; off <<= 1) {
        int t = __shfl_up(incl, off);
        if (lane >= off) incl += t;
    }
    if (lane < P) partial[lane] = incl - v;
    if (lane == 63) *rowstartN = incl;
}

// per-chunk exclusive scan + global offset; writes rowstart and cursor
__global__ __launch_bounds__(256) void chunk_scan(const int* __restrict__ deg,
                                                  const int* __restrict__ partial,
                                                  int* __restrict__ rowstart,
                                                  int* __restrict__ cursor, int N) {
    int base = blockIdx.x * 1024 + threadIdx.x * 4;
    int v[4];
    #pragma unroll
    for (int j = 0; j < 4; ++j) {
        int i = base + j;
        v[j] = (i < N) ? deg[i] : 0;
    }
    int mysum = v[0] + v[1] + v[2] + v[3];
    int incl = mysum;
    int lane = threadIdx.x & 63, wave = threadIdx.x >> 6;
    #pragma unroll
    for (int off = 1; off < 64; off <<= 1) {
        int t = __shfl_up(incl, off);
        if (lane >= off) incl += t;
    }
    __shared__ int ws[4];
    if (lane == 63) ws[wave] = incl;
    __syncthreads();
    int run = partial[blockIdx.x] + incl - mysum;
    for (int w = 0; w < wave; ++w) run += ws[w];
    #pragma unroll
    for (int j = 0; j < 4; ++j) {
        int i = base + j;
        if (i < N) { rowstart[i] = run; cursor[i] = run; }
        run += v[j];
    }
}

__global__ void bucket_kernel(const int* __restrict__ src, const int* __restrict__ dst,
                              int* __restrict__ cursor, int* __restrict__ ebuf, int E) {
    int e = blockIdx.x * 256 + threadIdx.x;
    if (e < E) {
        int pos = atomicAdd(&cursor[dst[e]], 1);
        ebuf[pos] = src[e];
    }
}

// ---------------- dtype conversion ----------------

__global__ void cvt_bf16_kernel(const float* __restrict__ in, unsigned short* __restrict__ out, int n4) {
    int i = blockIdx.x * 256 + threadIdx.x;
    if (i < n4) {
        float4 v = ((const float4*)in)[i];
        ushort4 o;
        o.x = (unsigned short)f2bf(v.x);
        o.y = (unsigned short)f2bf(v.y);
        o.z = (unsigned short)f2bf(v.z);
        o.w = (unsigned short)f2bf(v.w);
        ((ushort4*)out)[i] = o;
    }
}

// ---------------- gather means ----------------

// one wave per dst row; bf16 xb [N,128] -> bf16 mean [N,128]; fp32 accum
__global__ void gather_mean_128(const int* __restrict__ rowstart, const int* __restrict__ ebuf,
                                const unsigned* __restrict__ featb, unsigned* __restrict__ outb, int N) {
    int w = (blockIdx.x * blockDim.x + threadIdx.x) >> 6;
    int lane = threadIdx.x & 63;
    if (w >= N) return;
    int e0 = rowstart[w], e1 = rowstart[w + 1];
    float ax = 0.0f, ay = 0.0f;
    for (int i = e0; i < e1; ++i) {
        int s = ebuf[i];
        unsigned v = featb[(size_t)s * 64 + lane];   // 2 bf16
        ax += bf2f_lo(v); ay += bf2f_hi(v);
    }
    float inv = 1.0f / fmaxf((float)(e1 - e0), 1.0f);
    outb[(size_t)w * 64 + lane] = f2bf(ax * inv) | (f2bf(ay * inv) << 16);
}

// one wave per dst row; bf16 feat [N,512] -> bf16 mean [N,512]; fp32 accum
__global__ void gather_mean_512(const int* __restrict__ rowstart, const int* __restrict__ ebuf,
                                const unsigned short* __restrict__ featb,
                                unsigned short* __restrict__ outb, int N) {
    int w = (blockIdx.x * blockDim.x + threadIdx.x) >> 6;
    int lane = threadIdx.x & 63;
    if (w >= N) return;
    int e0 = rowstart[w], e1 = rowstart[w + 1];
    float a[8] = {0, 0, 0, 0, 0, 0, 0, 0};
    const uint4* base = (const uint4*)featb;     // 512 bf16/row = 64 uint4/row
    for (int i = e0; i < e1; ++i) {
        int s = ebuf[i];
        uint4 v = base[(size_t)s * 64 + lane];
        a[0] += bf2f_lo(v.x); a[1] += bf2f_hi(v.x);
        a[2] += bf2f_lo(v.y); a[3] += bf2f_hi(v.y);
        a[4] += bf2f_lo(v.z); a[5] += bf2f_hi(v.z);
        a[6] += bf2f_lo(v.w); a[7] += bf2f_hi(v.w);
    }
    float inv = 1.0f / fmaxf((float)(e1 - e0), 1.0f);
    uint4 o;
    o.x = f2bf(a[0] * inv) | (f2bf(a[1] * inv) << 16);
    o.y = f2bf(a[2] * inv) | (f2bf(a[3] * inv) << 16);
    o.z = f2bf(a[4] * inv) | (f2bf(a[5] * inv) << 16);
    o.w = f2bf(a[6] * inv) | (f2bf(a[7] * inv) << 16);
    ((uint4*)outb)[(size_t)w * 64 + lane] = o;
}

// ---------------- bf16 MFMA GEMM (R3 body, BK=32) ----------------
// C = relu([A0b | A1b] @ Wb^T + b)
// mode 0: store C as bf16 to outb [N, C]
// mode 1: logit[row] += sum_col C[row,col] * Wo[col]
// Block 256 thr = 4 waves (2x2); tile 128x128; wave tile 64x64 (4x4 mfma); BK=32.
// grid = (colblk fast, rowblk slow): A-tile siblings dispatch-concurrent.
__global__ __launch_bounds__(256) void gemm_mfma(
    const unsigned short* __restrict__ A0,   // [N, K0] bf16
    const unsigned short* __restrict__ A1,   // [N, K1] bf16
    const unsigned short* __restrict__ W,    // [C, K0+K1] bf16 row-major
    const float* __restrict__ b,             // [C] fp32
    unsigned short* __restrict__ outb,       // [N, C] bf16 (mode 0)
    const float* __restrict__ Wo,            // [C] fp32    (mode 1)
    float* __restrict__ logit,               // [N] fp32    (mode 1)
    int N, int K0, int K1, int C, int mode)
{
    const int K = K0 + K1;
    // row stride 40 shorts = 80 B (16B-aligned; 2-way lane aliasing is free)
    __shared__ short As[128 * 40];
    __shared__ short Bs[128 * 40];

    const int tid  = threadIdx.x;
    const int lane = tid & 63;
    const int wave = tid >> 6;
    const int wm = wave & 1, wn = wave >> 1;
    const int cl = lane & 15, quad = lane >> 4;
    const int row0 = blockIdx.y * 128;     // rowblk is the SLOW grid dim
    const int col0 = blockIdx.x * 128;     // colblk is the FAST grid dim

    // staging: thread t loads 16 bf16 of one row-half (k offset shalf*16)
    const int srow  = tid >> 1;     // 0..127
    const int shalf = tid & 1;      // 0/1
    const int arow = row0 + srow;
    const bool aok = arow < N;
    const int wcol = col0 + srow;   // C multiple of 128 -> always valid

    f32x4 acc[4][4];
    #pragma unroll
    for (int mt = 0; mt < 4; ++mt)
        #pragma unroll
        for (int nt = 0; nt < 4; ++nt)
            acc[mt][nt] = (f32x4){0.f, 0.f, 0.f, 0.f};

    for (int k0 = 0; k0 < K; k0 += 32) {
        const int gk = k0 + shalf * 16;
        uint4 av0 = {0, 0, 0, 0}, av1 = {0, 0, 0, 0};
        if (aok) {
            if (gk < K0) {      // block-uniform (K0, k0 multiples of 32)
                const uint4* p = (const uint4*)(A0 + (size_t)arow * K0 + gk);
                av0 = p[0]; av1 = p[1];
            } else {
                const uint4* p = (const uint4*)(A1 + (size_t)arow * K1 + (gk - K0));
                av0 = p[0]; av1 = p[1];
            }
        }
        const uint4* wp = (const uint4*)(W + (size_t)wcol * K + gk);
        uint4 wv0 = wp[0], wv1 = wp[1];

        __syncthreads();    // previous iteration's frag reads done
        *(uint4*)&As[srow * 40 + shalf * 16 + 0] = av0;
        *(uint4*)&As[srow * 40 + shalf * 16 + 8] = av1;
        *(uint4*)&Bs[srow * 40 + shalf * 16 + 0] = wv0;
        *(uint4*)&Bs[srow * 40 + shalf * 16 + 8] = wv1;
        __syncthreads();

        bf16x8 af[4], bfr[4];
        #pragma unroll
        for (int mt = 0; mt < 4; ++mt)
            af[mt] = *(const bf16x8*)&As[(wm * 64 + mt * 16 + cl) * 40 + quad * 8];
        #pragma unroll
        for (int nt = 0; nt < 4; ++nt)
            bfr[nt] = *(const bf16x8*)&Bs[(wn * 64 + nt * 16 + cl) * 40 + quad * 8];

        #pragma unroll
        for (int mt = 0; mt < 4; ++mt)
            #pragma unroll
            for (int nt = 0; nt < 4; ++nt)
                acc[mt][nt] = __builtin_amdgcn_mfma_f32_16x16x32_bf16(
                    af[mt], bfr[nt], acc[mt][nt], 0, 0, 0);
    }

    if (mode == 0) {
        #pragma unroll
        for (int nt = 0; nt < 4; ++nt) {
            const int colb = col0 + wn * 64 + nt * 16 + cl;
            const float bb = b[colb];
            #pragma unroll
            for (int mt = 0; mt < 4; ++mt) {
                #pragma unroll
                for (int r = 0; r < 4; ++r) {
                    int row = row0 + wm * 64 + mt * 16 + quad * 4 + r;
                    if (row < N)
                        outb[(size_t)row * C + colb] =
                            (unsigned short)f2bf(fmaxf(acc[mt][nt][r] + bb, 0.0f));
                }
            }
        }
    } else {
        float bv[4], wv2[4];
        #pragma unroll
        for (int nt = 0; nt < 4; ++nt) {
            const int colb = col0 + wn * 64 + nt * 16 + cl;
            bv[nt] = b[colb];
            wv2[nt] = Wo[colb];
        }
        #pragma unroll
        for (int mt = 0; mt < 4; ++mt) {
            #pragma unroll
            for (int r = 0; r < 4; ++r) {
                float s = 0.0f;
                #pragma unroll
                for (int nt = 0; nt < 4; ++nt)
                    s += fmaxf(acc[mt][nt][r] + bv[nt], 0.0f) * wv2[nt];
                s += __shfl_xor(s, 1);
                s += __shfl_xor(s, 2);
                s += __shfl_xor(s, 4);
                s += __shfl_xor(s, 8);
                int row = row0 + wm * 64 + mt * 16 + quad * 4 + r;
                if (cl == 0 && row < N) atomicAdd(&logit[row], s);
            }
        }
    }
}

__global__ void head_kernel(const float* __restrict__ logit, const float* __restrict__ bo,
                            float* __restrict__ out, int N) {
    int i = blockIdx.x * 256 + threadIdx.x;
    if (i < N) out[i] = 1.0f / (1.0f + expf(-(logit[i] + bo[0])));
}

extern "C" void kernel_launch(void* const* d_in, const int* in_sizes, int n_in,
                              void* d_out, int out_size, void* d_ws, size_t ws_size,
                              hipStream_t stream) {
    const float* x  = (const float*)d_in[0];
    const int*   ei = (const int*)d_in[1];
    const float* W1 = (const float*)d_in[2];
    const float* b1 = (const float*)d_in[3];
    const float* W2 = (const float*)d_in[4];
    const float* b2 = (const float*)d_in[5];
    const float* Wo = (const float*)d_in[6];
    const float* bo = (const float*)d_in[7];
    float* out = (float*)d_out;

    const int N = in_sizes[0] / 128;   // 50000
    const int E = in_sizes[1] / 2;     // 400000
    const int* src = ei;
    const int* dst = ei + E;

    char* ws = (char*)d_ws;
    size_t off = 0;
    auto alloc = [&](size_t bytes) {
        void* p = ws + off;
        off += (bytes + 255) & ~(size_t)255;
        return p;
    };
    int* deg      = (int*)alloc((size_t)N * 4);
    int* rowstart = (int*)alloc((size_t)(N + 1) * 4);
    int* cursor   = (int*)alloc((size_t)N * 4);
    int* partial  = (int*)alloc((size_t)64 * 4);
    int* ebuf     = (int*)alloc((size_t)E * 4);
    float* logit  = (float*)alloc((size_t)N * 4);
    unsigned short* xb  = (unsigned short*)alloc((size_t)N * 128 * 2);
    unsigned short* W1b = (unsigned short*)alloc((size_t)512 * 256 * 2);
    unsigned short* W2b = (unsigned short*)alloc((size_t)512 * 1024 * 2);
    unsigned short* n1b = (unsigned short*)alloc((size_t)N * 128 * 2);
    unsigned short* h1b = (unsigned short*)alloc((size_t)N * 512 * 2);
    unsigned short* n2b = (unsigned short*)alloc((size_t)N * 512 * 2);
    (void)ws_size; (void)n_in; (void)out_size;

    hipMemsetAsync(deg,   0, (size_t)N * 4, stream);
    hipMemsetAsync(logit, 0, (size_t)N * 4, stream);

    // conversions
    cvt_bf16_kernel<<<ceil_div(N * 128 / 4, 256), 256, 0, stream>>>(x, xb, N * 128 / 4);
    cvt_bf16_kernel<<<ceil_div(512 * 256 / 4, 256), 256, 0, stream>>>(W1, W1b, 512 * 256 / 4);
    cvt_bf16_kernel<<<ceil_div(512 * 1024 / 4, 256), 256, 0, stream>>>(W2, W2b, 512 * 1024 / 4);

    // CSR build (hierarchical scan)
    const int P = ceil_div(N, 1024);   // 49
    hist_kernel<<<ceil_div(E, 256), 256, 0, stream>>>(dst, deg, E);
    chunk_reduce<<<P, 256, 0, stream>>>(deg, partial, N);
    partial_scan<<<1, 64, 0, stream>>>(partial, rowstart + N, P);
    chunk_scan<<<P, 256, 0, stream>>>(deg, partial, rowstart, cursor, N);
    bucket_kernel<<<ceil_div(E, 256), 256, 0, stream>>>(src, dst, cursor, ebuf, E);

    dim3 gg(512 / 128, ceil_div(N, 128));   // (colblk fast, rowblk slow)

    // layer 1
    gather_mean_128<<<ceil_div(N * 64, 256), 256, 0, stream>>>(rowstart, ebuf,
                                                               (const unsigned*)xb, (unsigned*)n1b, N);
    gemm_mfma<<<gg, 256, 0, stream>>>(xb, n1b, W1b, b1, h1b, nullptr, nullptr,
                                      N, 128, 128, 512, 0);

    // layer 2 + fused head
    gather_mean_512<<<ceil_div(N * 64, 256), 256, 0, stream>>>(rowstart, ebuf, h1b, n2b, N);
    gemm_mfma<<<gg, 256, 0, stream>>>(h1b, n2b, W2b, b2, nullptr, Wo, logit,
                                      N, 512, 512, 512, 1);

    head_kernel<<<ceil_div(N, 256), 256, 0, stream>>>(logit, bo, out, N);
}